// Round 1
// baseline (439.035 us; speedup 1.0000x reference)
//
#include <hip/hip_runtime.h>

#define B_ 64
#define T_ 512
#define D_ 768
#define K_ 21
#define WPAD 772   // 768 + 4 floats: keeps 16B alignment, breaks 32-bank stride

// ---------------- Kernel 1: logits[32768,21] = A[32768,768] @ W^T + b ----------
// thread q -> k = q%21, rowgroup g = q/21 (4 rows each). Lanes 0..20 of a wave
// share rows -> A loads broadcast; W column streamed from LDS (ds_read_b128).
__global__ __launch_bounds__(256) void proj_kernel(
    const float* __restrict__ A,
    const float* __restrict__ W,
    const float* __restrict__ bias,
    float* __restrict__ out)            // d_out: [0]=loss, [1..]=logits
{
    __shared__ float Wl[K_ * WPAD];
    const int tid = threadIdx.x;
    for (int idx = tid; idx < K_ * D_; idx += 256) {
        int k = idx / D_;
        int d = idx - k * D_;
        Wl[k * WPAD + d] = W[idx];
    }
    __syncthreads();

    const int q = blockIdx.x * 256 + tid;      // 672*256 == 8192*21 exactly
    const int k = q % K_;
    const int g = q / K_;
    const int row0 = g * 4;

    const float4* __restrict__ a0 = (const float4*)(A + (size_t)(row0 + 0) * D_);
    const float4* __restrict__ a1 = (const float4*)(A + (size_t)(row0 + 1) * D_);
    const float4* __restrict__ a2 = (const float4*)(A + (size_t)(row0 + 2) * D_);
    const float4* __restrict__ a3 = (const float4*)(A + (size_t)(row0 + 3) * D_);
    const float4* wp = (const float4*)(&Wl[k * WPAD]);

    float acc0 = 0.f, acc1 = 0.f, acc2 = 0.f, acc3 = 0.f;
    #pragma unroll 4
    for (int d4 = 0; d4 < D_ / 4; ++d4) {
        const float4 w  = wp[d4];
        const float4 x0 = a0[d4];
        const float4 x1 = a1[d4];
        const float4 x2 = a2[d4];
        const float4 x3 = a3[d4];
        acc0 += x0.x * w.x + x0.y * w.y + x0.z * w.z + x0.w * w.w;
        acc1 += x1.x * w.x + x1.y * w.y + x1.z * w.z + x1.w * w.w;
        acc2 += x2.x * w.x + x2.y * w.y + x2.z * w.z + x2.w * w.w;
        acc3 += x3.x * w.x + x3.y * w.y + x3.z * w.z + x3.w * w.w;
    }
    const float bb = bias[k];
    float* o = out + 1 + (size_t)row0 * K_ + k;
    o[0]        = acc0 + bb;
    o[K_]       = acc1 + bb;
    o[2 * K_]   = acc2 + bb;
    o[3 * K_]   = acc3 + bb;
}

// ---------------- Kernel 2: per-batch CRF forward + gold score ------------------
// One wave per batch. Lane j owns alpha[j] (j<21; lanes>=21 mirror lane 20).
// alpha kept relative to running scalar offset C -> no per-step max reduction.
// new_alpha[j] = C + log( sum_i exp(aRel_i) * exp(trans[i][j]) ) + emit[j]
__global__ __launch_bounds__(64) void crf_kernel(
    const float* __restrict__ outF,     // d_out (logits at +1)
    const int*   __restrict__ tags,
    const int*   __restrict__ mask,
    const float* __restrict__ trans,
    const float* __restrict__ startT,
    const float* __restrict__ endT,
    float* __restrict__ ws)             // ws[0..63]=ll_b, ws[64..127]=masksum_b
{
    __shared__ float se[T_ * K_];       // emits for this batch (43 KB)
    __shared__ float sm[T_];
    __shared__ int   st[T_];
    const int b = blockIdx.x;
    const int lane = threadIdx.x;

    const float* lg = outF + 1 + (size_t)b * T_ * K_;
    for (int i = lane; i < T_ * K_; i += 64) se[i] = lg[i];
    for (int t = lane; t < T_; t += 64) {
        sm[t] = (float)mask[b * T_ + t];
        st[t] = tags[b * T_ + t];
    }
    __syncthreads();

    const int jc = lane < K_ ? lane : K_ - 1;

    float ET[K_];                        // column jc of exp(transitions)
    #pragma unroll
    for (int i = 0; i < K_; ++i) ET[i] = __expf(trans[i * K_ + jc]);

    float a0   = startT[jc] + se[jc];
    float r0   = __shfl(a0, 0, 64);
    float aRel = a0 - r0;
    float C    = r0;

    for (int t = 1; t < T_; ++t) {
        if (sm[t] != 0.0f) {             // wave-uniform branch
            float e = __expf(aRel);
            float s = 0.0f;
            #pragma unroll
            for (int i = 0; i < K_; ++i)
                s = fmaf(__shfl(e, i, 64), ET[i], s);
            float raw = __logf(s) + se[t * K_ + jc];
            float rr  = __shfl(raw, 0, 64);
            aRel = raw - rr;
            C   += rr;
        }
    }

    // log-partition
    float contrib = (lane < K_) ? __expf(aRel + endT[jc]) : 0.0f;
    #pragma unroll
    for (int off = 32; off >= 1; off >>= 1)
        contrib += __shfl_xor(contrib, off, 64);
    const float logZ = C + __logf(contrib);

    // gold-path score + mask sum (lanes parallel over t)
    float sc = 0.0f, ms = 0.0f;
    for (int t = lane; t < T_; t += 64) {
        const float mt = sm[t];
        ms += mt;
        if (t < T_ - 1) {
            const int ct = st[t], nt2 = st[t + 1];
            sc += trans[ct * K_ + nt2] * sm[t + 1] + se[t * K_ + ct] * mt;
        }
    }
    #pragma unroll
    for (int off = 32; off >= 1; off >>= 1) {
        sc += __shfl_xor(sc, off, 64);
        ms += __shfl_xor(ms, off, 64);
    }
    if (lane == 0) {
        const int lastIdx = (int)ms - 1;
        const int lastTag = st[lastIdx];
        sc += startT[st[0]] + endT[lastTag] + se[(T_ - 1) * K_ + lastTag] * sm[T_ - 1];
        ws[b]      = sc - logZ;
        ws[B_ + b] = ms;
    }
}

// ---------------- Kernel 3: loss = -sum(ll) / sum(mask) ------------------------
__global__ __launch_bounds__(64) void fin_kernel(
    const float* __restrict__ ws, float* __restrict__ outF)
{
    const int lane = threadIdx.x;
    float ll = ws[lane];
    float ms = ws[B_ + lane];
    #pragma unroll
    for (int off = 32; off >= 1; off >>= 1) {
        ll += __shfl_xor(ll, off, 64);
        ms += __shfl_xor(ms, off, 64);
    }
    if (lane == 0) outF[0] = -ll / ms;
}

extern "C" void kernel_launch(void* const* d_in, const int* in_sizes, int n_in,
                              void* d_out, int out_size, void* d_ws, size_t ws_size,
                              hipStream_t stream) {
    const float* A     = (const float*)d_in[0];   // vectors [64,512,768] f32
    const int*   tags  = (const int*)  d_in[1];   // targets [64,512] i32
    const int*   mask  = (const int*)  d_in[2];   // mask    [64,512] i32
    const float* W     = (const float*)d_in[3];   // W [21,768] f32
    const float* bias  = (const float*)d_in[4];   // b [21]
    const float* trans = (const float*)d_in[5];   // transitions [21,21]
    const float* stT   = (const float*)d_in[6];   // start_trans [21]
    const float* enT   = (const float*)d_in[7];   // end_trans [21]
    float* outF = (float*)d_out;
    float* ws   = (float*)d_ws;

    proj_kernel<<<672, 256, 0, stream>>>(A, W, bias, outF);
    crf_kernel<<<B_, 64, 0, stream>>>(outF, tags, mask, trans, stT, enT, ws);
    fin_kernel<<<1, 64, 0, stream>>>(ws, outF);
}

// Round 2
// 302.411 us; speedup vs baseline: 1.4518x; 1.4518x over previous
//
#include <hip/hip_runtime.h>

#define B_ 64
#define T_ 512
#define D_ 768
#define K_ 21
#define WPAD 772     // 768 + 4 floats
#define NCHUNK 32    // chunks over t=1..511
#define CLEN 16      // steps per chunk
#define GSTRIDE 448  // padded 21*21
#define LOG21 3.0445224377234229965f

// ---------------- Kernel 1: logits[32768,21] = A[32768,768] @ W^T + b ----------
__global__ __launch_bounds__(256) void proj_kernel(
    const float* __restrict__ A,
    const float* __restrict__ W,
    const float* __restrict__ bias,
    float* __restrict__ out)            // d_out: [0]=loss, [1..]=logits
{
    __shared__ float Wl[K_ * WPAD];
    const int tid = threadIdx.x;
    for (int idx = tid; idx < K_ * D_; idx += 256) {
        int k = idx / D_;
        int d = idx - k * D_;
        Wl[k * WPAD + d] = W[idx];
    }
    __syncthreads();

    const int q = blockIdx.x * 256 + tid;      // 672*256 == 8192*21 exactly
    const int k = q % K_;
    const int g = q / K_;
    const int row0 = g * 4;

    const float4* __restrict__ a0 = (const float4*)(A + (size_t)(row0 + 0) * D_);
    const float4* __restrict__ a1 = (const float4*)(A + (size_t)(row0 + 1) * D_);
    const float4* __restrict__ a2 = (const float4*)(A + (size_t)(row0 + 2) * D_);
    const float4* __restrict__ a3 = (const float4*)(A + (size_t)(row0 + 3) * D_);
    const float4* wp = (const float4*)(&Wl[k * WPAD]);

    float acc0 = 0.f, acc1 = 0.f, acc2 = 0.f, acc3 = 0.f;
    #pragma unroll 4
    for (int d4 = 0; d4 < D_ / 4; ++d4) {
        const float4 w  = wp[d4];
        const float4 x0 = a0[d4];
        const float4 x1 = a1[d4];
        const float4 x2 = a2[d4];
        const float4 x3 = a3[d4];
        acc0 += x0.x * w.x + x0.y * w.y + x0.z * w.z + x0.w * w.w;
        acc1 += x1.x * w.x + x1.y * w.y + x1.z * w.z + x1.w * w.w;
        acc2 += x2.x * w.x + x2.y * w.y + x2.z * w.z + x2.w * w.w;
        acc3 += x3.x * w.x + x3.y * w.y + x3.z * w.z + x3.w * w.w;
    }
    const float bb = bias[k];
    float* o = out + 1 + (size_t)row0 * K_ + k;
    o[0]        = acc0 + bb;
    o[K_]       = acc1 + bb;
    o[2 * K_]   = acc2 + bb;
    o[3 * K_]   = acc3 + bb;
}

// ---------------- Kernel 2a: per-(batch,chunk) transfer-matrix product --------
// G_c = Prod_{t in chunk, mask=1} (ET * diag(em_t)) / 21^n, em normalized by
// per-step max. One wave per task; lane l<63 -> (row i = l/3, colgroup jg = l%3)
// owns 7 output entries. ET columns held in registers (147 VGPRs).
__global__ __launch_bounds__(64) void chunk_kernel(
    const float* __restrict__ outF,
    const int*   __restrict__ mask,
    const float* __restrict__ trans,
    float* __restrict__ G,
    float* __restrict__ SC)
{
    __shared__ float M0[441], M1[441];
    __shared__ float em[CLEN * K_];
    __shared__ float smx[CLEN];
    __shared__ int   smask[CLEN];

    const int c = blockIdx.x;
    const int b = blockIdx.y;
    const int lane = threadIdx.x;
    const int t0 = c * CLEN + 1;
    const int nst = min(CLEN, T_ - t0);     // 16, except 15 for last chunk
    const int i_ = lane / 3;
    const int jg = lane - i_ * 3;
    const bool act = lane < 63;

    const float* lg = outF + 1 + (size_t)b * T_ * K_;
    for (int idx = lane; idx < nst * K_; idx += 64) em[idx] = lg[t0 * K_ + idx];
    if (lane < nst) smask[lane] = mask[b * T_ + t0 + lane];
    for (int idx = lane; idx < 441; idx += 64)
        M0[idx] = (idx % 22 == 0) ? 1.0f : 0.0f;     // identity
    __syncthreads();

    if (lane < nst) {
        float mx = -1e30f;
        for (int j = 0; j < K_; ++j) mx = fmaxf(mx, em[lane * K_ + j]);
        smx[lane] = mx;
    }
    __syncthreads();
    for (int idx = lane; idx < nst * K_; idx += 64)
        em[idx] = __expf(em[idx] - smx[idx / K_]) * (1.0f / 21.0f);

    float ETc[K_ * 7];
    if (act) {
        #pragma unroll
        for (int m = 0; m < K_; ++m) {
            #pragma unroll
            for (int q = 0; q < 7; ++q)
                ETc[m * 7 + q] = __expf(trans[m * K_ + jg * 7 + q]);
        }
    }
    __syncthreads();

    int cur = 0;
    for (int s = 0; s < nst; ++s) {
        if (smask[s] != 0) {                 // wave-uniform
            const float* Mr = cur ? M1 : M0;
            float*       Mw = cur ? M0 : M1;
            float acc[7] = {0.f,0.f,0.f,0.f,0.f,0.f,0.f};
            if (act) {
                #pragma unroll
                for (int m = 0; m < K_; ++m) {
                    const float lm = Mr[i_ * K_ + m];
                    #pragma unroll
                    for (int q = 0; q < 7; ++q)
                        acc[q] = fmaf(lm, ETc[m * 7 + q], acc[q]);
                }
            }
            __syncthreads();                 // reads of Mr done before Mw overwrite next round
            if (act) {
                #pragma unroll
                for (int q = 0; q < 7; ++q)
                    Mw[i_ * K_ + jg * 7 + q] = acc[q] * em[s * K_ + jg * 7 + q];
            }
            __syncthreads();                 // writes visible before next reads
            cur ^= 1;
        }
    }

    float* Gc = G + (size_t)(b * NCHUNK + c) * GSTRIDE;
    const float* Mf = cur ? M1 : M0;
    for (int idx = lane; idx < 441; idx += 64) Gc[idx] = Mf[idx];
    if (lane == 0) {
        float sc = 0.0f;
        for (int s = 0; s < nst; ++s)
            if (smask[s] != 0) sc += smx[s] + LOG21;
        SC[b * NCHUNK + c] = sc;
    }
}

// ---------------- Kernel 2b: 32-step scan + gold score per batch ---------------
__global__ __launch_bounds__(64) void scan_kernel(
    const float* __restrict__ outF,
    const int*   __restrict__ tags,
    const int*   __restrict__ mask,
    const float* __restrict__ trans,
    const float* __restrict__ startT,
    const float* __restrict__ endT,
    const float* __restrict__ G,
    const float* __restrict__ SC,
    float* __restrict__ ll,
    float* __restrict__ msum)
{
    __shared__ float sv[24];
    __shared__ float sm[T_];
    __shared__ int   st[T_];
    const int b = blockIdx.x;
    const int lane = threadIdx.x;
    const int jc = min(lane, K_ - 1);
    const float* lg = outF + 1 + (size_t)b * T_ * K_;

    for (int t = lane; t < T_; t += 64) {
        sm[t] = (float)mask[b * T_ + t];
        st[t] = tags[b * T_ + t];
    }

    // v0 = exp(start + emit0 - max)
    float val = (lane < K_) ? startT[lane] + lg[lane] : -1e30f;
    float mx = val;
    #pragma unroll
    for (int off = 32; off >= 1; off >>= 1) mx = fmaxf(mx, __shfl_xor(mx, off, 64));
    float v = (lane < K_) ? __expf(val - mx) : 0.0f;
    float C = mx;
    __syncthreads();

    for (int c = 0; c < NCHUNK; ++c) {
        if (lane < K_) sv[lane] = v;
        __syncthreads();
        const float* Gc = G + (size_t)(b * NCHUNK + c) * GSTRIDE + jc;
        float a0 = 0.f, a1 = 0.f, a2 = 0.f;
        #pragma unroll
        for (int i = 0; i < K_; i += 3) {
            a0 = fmaf(sv[i],     Gc[i * K_],       a0);
            a1 = fmaf(sv[i + 1], Gc[(i + 1) * K_], a1);
            a2 = fmaf(sv[i + 2], Gc[(i + 2) * K_], a2);
        }
        const float s = a0 + a1 + a2;
        C += SC[b * NCHUNK + c];
        float m2 = (lane < K_) ? s : 0.0f;
        #pragma unroll
        for (int off = 32; off >= 1; off >>= 1) m2 = fmaxf(m2, __shfl_xor(m2, off, 64));
        v = (lane < K_) ? s / m2 : 0.0f;
        C += __logf(m2);
        __syncthreads();     // all lanes done with sv before next overwrite
    }

    float term = (lane < K_) ? v * __expf(endT[lane]) : 0.0f;
    #pragma unroll
    for (int off = 32; off >= 1; off >>= 1) term += __shfl_xor(term, off, 64);
    const float logZ = C + __logf(term);

    // gold-path score + mask sum
    float sc = 0.0f, ms = 0.0f;
    for (int t = lane; t < T_; t += 64) {
        const float mt = sm[t];
        ms += mt;
        if (t < T_ - 1) {
            const int ct = st[t], nt2 = st[t + 1];
            sc += trans[ct * K_ + nt2] * sm[t + 1] + lg[t * K_ + ct] * mt;
        }
    }
    #pragma unroll
    for (int off = 32; off >= 1; off >>= 1) {
        sc += __shfl_xor(sc, off, 64);
        ms += __shfl_xor(ms, off, 64);
    }
    if (lane == 0) {
        const int lastIdx = (int)ms - 1;
        const int lastTag = st[lastIdx];
        sc += startT[st[0]] + endT[lastTag] + lg[(T_ - 1) * K_ + lastTag] * sm[T_ - 1];
        ll[b]   = sc - logZ;
        msum[b] = ms;
    }
}

// ---------------- Fallback (R1): per-batch sequential CRF ----------------------
__global__ __launch_bounds__(64) void crf_kernel(
    const float* __restrict__ outF,
    const int*   __restrict__ tags,
    const int*   __restrict__ mask,
    const float* __restrict__ trans,
    const float* __restrict__ startT,
    const float* __restrict__ endT,
    float* __restrict__ ws)
{
    __shared__ float se[T_ * K_];
    __shared__ float sm[T_];
    __shared__ int   st[T_];
    const int b = blockIdx.x;
    const int lane = threadIdx.x;

    const float* lg = outF + 1 + (size_t)b * T_ * K_;
    for (int i = lane; i < T_ * K_; i += 64) se[i] = lg[i];
    for (int t = lane; t < T_; t += 64) {
        sm[t] = (float)mask[b * T_ + t];
        st[t] = tags[b * T_ + t];
    }
    __syncthreads();

    const int jc = lane < K_ ? lane : K_ - 1;
    float ET[K_];
    #pragma unroll
    for (int i = 0; i < K_; ++i) ET[i] = __expf(trans[i * K_ + jc]);

    float a0   = startT[jc] + se[jc];
    float r0   = __shfl(a0, 0, 64);
    float aRel = a0 - r0;
    float C    = r0;

    for (int t = 1; t < T_; ++t) {
        if (sm[t] != 0.0f) {
            float e = __expf(aRel);
            float s = 0.0f;
            #pragma unroll
            for (int i = 0; i < K_; ++i)
                s = fmaf(__shfl(e, i, 64), ET[i], s);
            float raw = __logf(s) + se[t * K_ + jc];
            float rr  = __shfl(raw, 0, 64);
            aRel = raw - rr;
            C   += rr;
        }
    }

    float contrib = (lane < K_) ? __expf(aRel + endT[jc]) : 0.0f;
    #pragma unroll
    for (int off = 32; off >= 1; off >>= 1) contrib += __shfl_xor(contrib, off, 64);
    const float logZ = C + __logf(contrib);

    float sc = 0.0f, ms = 0.0f;
    for (int t = lane; t < T_; t += 64) {
        const float mt = sm[t];
        ms += mt;
        if (t < T_ - 1) {
            const int ct = st[t], nt2 = st[t + 1];
            sc += trans[ct * K_ + nt2] * sm[t + 1] + se[t * K_ + ct] * mt;
        }
    }
    #pragma unroll
    for (int off = 32; off >= 1; off >>= 1) {
        sc += __shfl_xor(sc, off, 64);
        ms += __shfl_xor(ms, off, 64);
    }
    if (lane == 0) {
        const int lastIdx = (int)ms - 1;
        const int lastTag = st[lastIdx];
        sc += startT[st[0]] + endT[lastTag] + se[(T_ - 1) * K_ + lastTag] * sm[T_ - 1];
        ws[b]      = sc - logZ;
        ws[B_ + b] = ms;
    }
}

// ---------------- Kernel 3: loss = -sum(ll) / sum(mask) ------------------------
__global__ __launch_bounds__(64) void fin_kernel(
    const float* __restrict__ ll, const float* __restrict__ msum,
    float* __restrict__ outF)
{
    const int lane = threadIdx.x;
    float l = ll[lane];
    float m = msum[lane];
    #pragma unroll
    for (int off = 32; off >= 1; off >>= 1) {
        l += __shfl_xor(l, off, 64);
        m += __shfl_xor(m, off, 64);
    }
    if (lane == 0) outF[0] = -l / m;
}

extern "C" void kernel_launch(void* const* d_in, const int* in_sizes, int n_in,
                              void* d_out, int out_size, void* d_ws, size_t ws_size,
                              hipStream_t stream) {
    const float* A     = (const float*)d_in[0];   // vectors [64,512,768] f32
    const int*   tags  = (const int*)  d_in[1];   // targets [64,512] i32
    const int*   mask  = (const int*)  d_in[2];   // mask    [64,512] i32
    const float* W     = (const float*)d_in[3];   // W [21,768] f32
    const float* bias  = (const float*)d_in[4];   // b [21]
    const float* trans = (const float*)d_in[5];   // transitions [21,21]
    const float* stT   = (const float*)d_in[6];   // start_trans [21]
    const float* enT   = (const float*)d_in[7];   // end_trans [21]
    float* outF = (float*)d_out;
    float* ws   = (float*)d_ws;

    proj_kernel<<<672, 256, 0, stream>>>(A, W, bias, outF);

    // ws layout (floats): G[64*32*448] | SC[64*32] | ll[64] | ms[64]
    const size_t gFloats  = (size_t)B_ * NCHUNK * GSTRIDE;
    const size_t scOff    = gFloats;
    const size_t llOff    = gFloats + (size_t)B_ * NCHUNK;
    const size_t msOff    = llOff + B_;
    const size_t needBytes = (msOff + B_) * sizeof(float);

    if (ws_size >= needBytes) {
        float* G   = ws;
        float* SC  = ws + scOff;
        float* ll  = ws + llOff;
        float* msv = ws + msOff;
        chunk_kernel<<<dim3(NCHUNK, B_), 64, 0, stream>>>(outF, mask, trans, G, SC);
        scan_kernel<<<B_, 64, 0, stream>>>(outF, tags, mask, trans, stT, enT, G, SC, ll, msv);
        fin_kernel<<<1, 64, 0, stream>>>(ll, msv, outF);
    } else {
        crf_kernel<<<B_, 64, 0, stream>>>(outF, tags, mask, trans, stT, enT, ws);
        fin_kernel<<<1, 64, 0, stream>>>(ws, ws + B_, outF);
    }
}

// Round 3
// 218.349 us; speedup vs baseline: 2.0107x; 1.3850x over previous
//
#include <hip/hip_runtime.h>

#define B_ 64
#define T_ 512
#define D_ 768
#define K_ 21
#define NCHUNK 32    // chunks over t=1..511
#define CLEN 16      // steps per chunk
#define GSTRIDE 448  // padded 21*21
#define LOG21 3.0445224377234229965f

// ---------------- Kernel 1: logits[32768,21] = A[32768,768] @ W^T + b ----------
// lane -> (row = tid/16, slice m = tid%16). A loads: wave = 4 rows x 256B
// contiguous (coalesced float4, no LDS round trip). W in LDS. Thread accumulates
// all 21 k over its 48 cols; xor-shuffle reduce over the 16 slice lanes.
__global__ __launch_bounds__(512) void proj_kernel(
    const float* __restrict__ A,
    const float* __restrict__ W,
    const float* __restrict__ bias,
    float* __restrict__ out)            // d_out: [0]=loss, [1..]=logits
{
    __shared__ float Wl[K_ * D_];       // 63 KB
    const int tid = threadIdx.x;
    {
        const float4* Wg = (const float4*)W;
        float4* Ws = (float4*)Wl;
        for (int i = tid; i < K_ * D_ / 4; i += 512) Ws[i] = Wg[i];
    }
    __syncthreads();

    const int m = tid & 15;                       // col slice
    const size_t row = (size_t)blockIdx.x * 32 + (tid >> 4);
    const float4* __restrict__ Arow = (const float4*)(A + row * D_);
    const float4* __restrict__ Wl4 = (const float4*)Wl;

    float acc[K_];
    #pragma unroll
    for (int k = 0; k < K_; ++k) acc[k] = 0.0f;

    #pragma unroll 4
    for (int i = 0; i < 12; ++i) {
        const float4 a = Arow[m + 16 * i];
        #pragma unroll
        for (int k = 0; k < K_; ++k) {
            const float4 w = Wl4[k * 192 + m + 16 * i];
            acc[k] = fmaf(a.x, w.x, fmaf(a.y, w.y, fmaf(a.z, w.z, fmaf(a.w, w.w, acc[k]))));
        }
    }

    // reduce over the 16 slice lanes (offsets 1,2,4,8 stay within the group)
    #pragma unroll
    for (int k = 0; k < K_; ++k) {
        float v = acc[k];
        v += __shfl_xor(v, 1, 64);
        v += __shfl_xor(v, 2, 64);
        v += __shfl_xor(v, 4, 64);
        v += __shfl_xor(v, 8, 64);
        acc[k] = v;
    }

    float* o = out + 1 + row * K_;
    #pragma unroll
    for (int k = 0; k < K_; ++k) {
        if (m == (k & 15)) o[k] = acc[k] + bias[k];   // static reg index
    }
}

// ---------------- Kernel 2a: per-(batch,chunk) transfer-matrix product --------
// G_c = Prod_{t in chunk, mask=1} (ET * diag(em_t)) / 21^n, em normalized by
// per-step max. One wave per task; lane l<63 -> (row i = l/3, colgroup jg = l%3).
__global__ __launch_bounds__(64) void chunk_kernel(
    const float* __restrict__ outF,
    const int*   __restrict__ mask,
    const float* __restrict__ trans,
    float* __restrict__ G,
    float* __restrict__ SC)
{
    __shared__ float M0[441], M1[441];
    __shared__ float sET[441];
    __shared__ float em[CLEN * K_];
    __shared__ float smx[CLEN];
    __shared__ int   smask[CLEN];

    const int c = blockIdx.x;
    const int b = blockIdx.y;
    const int lane = threadIdx.x;
    const int t0 = c * CLEN + 1;
    const int nst = min(CLEN, T_ - t0);     // 16, except 15 for last chunk
    const int i_ = lane / 3;
    const int jg = lane - i_ * 3;
    const bool act = lane < 63;

    const float* lg = outF + 1 + (size_t)b * T_ * K_;
    for (int idx = lane; idx < nst * K_; idx += 64) em[idx] = lg[t0 * K_ + idx];
    if (lane < nst) smask[lane] = mask[b * T_ + t0 + lane];
    for (int idx = lane; idx < 441; idx += 64) {
        M0[idx] = (idx % 22 == 0) ? 1.0f : 0.0f;     // identity
        sET[idx] = __expf(trans[idx]);               // coalesced trans read
    }
    __syncthreads();

    if (lane < nst) {
        float mx = -1e30f;
        for (int j = 0; j < K_; ++j) mx = fmaxf(mx, em[lane * K_ + j]);
        smx[lane] = mx;
    }
    __syncthreads();
    for (int idx = lane; idx < nst * K_; idx += 64)
        em[idx] = __expf(em[idx] - smx[idx / K_]) * (1.0f / 21.0f);

    float ETc[K_ * 7];
    if (act) {
        #pragma unroll
        for (int mm = 0; mm < K_; ++mm) {
            #pragma unroll
            for (int q = 0; q < 7; ++q)
                ETc[mm * 7 + q] = sET[mm * K_ + jg * 7 + q];
        }
    }
    __syncthreads();

    int cur = 0;
    for (int s = 0; s < nst; ++s) {
        if (smask[s] != 0) {                 // wave-uniform
            const float* Mr = cur ? M1 : M0;
            float*       Mw = cur ? M0 : M1;
            float facc[7] = {0.f,0.f,0.f,0.f,0.f,0.f,0.f};
            if (act) {
                #pragma unroll
                for (int mm = 0; mm < K_; ++mm) {
                    const float lm = Mr[i_ * K_ + mm];
                    #pragma unroll
                    for (int q = 0; q < 7; ++q)
                        facc[q] = fmaf(lm, ETc[mm * 7 + q], facc[q]);
                }
            }
            __syncthreads();
            if (act) {
                #pragma unroll
                for (int q = 0; q < 7; ++q)
                    Mw[i_ * K_ + jg * 7 + q] = facc[q] * em[s * K_ + jg * 7 + q];
            }
            __syncthreads();
            cur ^= 1;
        }
    }

    float* Gc = G + (size_t)(b * NCHUNK + c) * GSTRIDE;
    const float* Mf = cur ? M1 : M0;
    for (int idx = lane; idx < 441; idx += 64) Gc[idx] = Mf[idx];
    if (lane == 0) {
        float sc = 0.0f;
        for (int s = 0; s < nst; ++s)
            if (smask[s] != 0) sc += smx[s] + LOG21;
        SC[b * NCHUNK + c] = sc;
    }
}

// ---------------- Kernel 2b: 32-step scan + gold score per batch ---------------
// G chunks double-buffered through LDS (loads issued one chunk ahead).
__global__ __launch_bounds__(64) void scan_kernel(
    const float* __restrict__ outF,
    const int*   __restrict__ tags,
    const int*   __restrict__ mask,
    const float* __restrict__ trans,
    const float* __restrict__ startT,
    const float* __restrict__ endT,
    const float* __restrict__ G,
    const float* __restrict__ SC,
    float* __restrict__ ll,
    float* __restrict__ msum)
{
    __shared__ float sG[2][GSTRIDE];
    __shared__ float sv[24];
    __shared__ float sm[T_];
    __shared__ int   st[T_];
    const int b = blockIdx.x;
    const int lane = threadIdx.x;
    const int jc = min(lane, K_ - 1);
    const float* lg = outF + 1 + (size_t)b * T_ * K_;
    const float* Gb = G + (size_t)b * NCHUNK * GSTRIDE;

    for (int t = lane; t < T_; t += 64) {
        sm[t] = (float)mask[b * T_ + t];
        st[t] = tags[b * T_ + t];
    }
    const float scv = (lane < NCHUNK) ? SC[b * NCHUNK + lane] : 0.0f;

    // stage chunk 0
    {
        const float4* Gf4 = (const float4*)Gb;           // 112 float4
        float4* dst = (float4*)sG[0];
        dst[lane] = Gf4[lane];
        if (lane < 48) dst[lane + 64] = Gf4[lane + 64];
    }

    // v0 = exp(start + emit0 - max)
    float val = (lane < K_) ? startT[lane] + lg[lane] : -1e30f;
    float mx = val;
    #pragma unroll
    for (int off = 32; off >= 1; off >>= 1) mx = fmaxf(mx, __shfl_xor(mx, off, 64));
    float v = (lane < K_) ? __expf(val - mx) : 0.0f;
    float C = mx;

    for (int c = 0; c < NCHUNK; ++c) {
        if (lane < K_) sv[lane] = v;
        __syncthreads();                      // sv + sG[c&1] ready

        // issue next chunk's loads (latency hidden behind compute)
        float4 p0, p1;
        const bool have = (c + 1) < NCHUNK;
        if (have) {
            const float4* Gf4 = (const float4*)(Gb + (size_t)(c + 1) * GSTRIDE);
            p0 = Gf4[lane];
            if (lane < 48) p1 = Gf4[lane + 64];
        }

        const float* Gc = sG[c & 1];
        float a0 = 0.f, a1 = 0.f, a2 = 0.f;
        #pragma unroll
        for (int i = 0; i < K_; i += 3) {
            a0 = fmaf(sv[i],     Gc[i * K_ + jc],       a0);
            a1 = fmaf(sv[i + 1], Gc[(i + 1) * K_ + jc], a1);
            a2 = fmaf(sv[i + 2], Gc[(i + 2) * K_ + jc], a2);
        }
        const float s = a0 + a1 + a2;
        C += __shfl(scv, c, 64);
        float m2 = (lane < K_) ? s : 0.0f;
        #pragma unroll
        for (int off = 32; off >= 1; off >>= 1) m2 = fmaxf(m2, __shfl_xor(m2, off, 64));
        v = (lane < K_) ? s / m2 : 0.0f;
        C += __logf(m2);

        if (have) {
            float4* dst = (float4*)sG[(c + 1) & 1];
            dst[lane] = p0;
            if (lane < 48) dst[lane + 64] = p1;
        }
        __syncthreads();                      // sv reads done; next buffer visible
    }

    float term = (lane < K_) ? v * __expf(endT[lane]) : 0.0f;
    #pragma unroll
    for (int off = 32; off >= 1; off >>= 1) term += __shfl_xor(term, off, 64);
    const float logZ = C + __logf(term);

    // gold-path score + mask sum
    float sc = 0.0f, ms = 0.0f;
    for (int t = lane; t < T_; t += 64) {
        const float mt = sm[t];
        ms += mt;
        if (t < T_ - 1) {
            const int ct = st[t], nt2 = st[t + 1];
            sc += trans[ct * K_ + nt2] * sm[t + 1] + lg[t * K_ + ct] * mt;
        }
    }
    #pragma unroll
    for (int off = 32; off >= 1; off >>= 1) {
        sc += __shfl_xor(sc, off, 64);
        ms += __shfl_xor(ms, off, 64);
    }
    if (lane == 0) {
        const int lastIdx = (int)ms - 1;
        const int lastTag = st[lastIdx];
        sc += startT[st[0]] + endT[lastTag] + lg[(T_ - 1) * K_ + lastTag] * sm[T_ - 1];
        ll[b]   = sc - logZ;
        msum[b] = ms;
    }
}

// ---------------- Fallback (R1): per-batch sequential CRF ----------------------
__global__ __launch_bounds__(64) void crf_kernel(
    const float* __restrict__ outF,
    const int*   __restrict__ tags,
    const int*   __restrict__ mask,
    const float* __restrict__ trans,
    const float* __restrict__ startT,
    const float* __restrict__ endT,
    float* __restrict__ ws)
{
    __shared__ float se[T_ * K_];
    __shared__ float sm[T_];
    __shared__ int   st[T_];
    const int b = blockIdx.x;
    const int lane = threadIdx.x;

    const float* lg = outF + 1 + (size_t)b * T_ * K_;
    for (int i = lane; i < T_ * K_; i += 64) se[i] = lg[i];
    for (int t = lane; t < T_; t += 64) {
        sm[t] = (float)mask[b * T_ + t];
        st[t] = tags[b * T_ + t];
    }
    __syncthreads();

    const int jc = lane < K_ ? lane : K_ - 1;
    float ET[K_];
    #pragma unroll
    for (int i = 0; i < K_; ++i) ET[i] = __expf(trans[i * K_ + jc]);

    float a0   = startT[jc] + se[jc];
    float r0   = __shfl(a0, 0, 64);
    float aRel = a0 - r0;
    float C    = r0;

    for (int t = 1; t < T_; ++t) {
        if (sm[t] != 0.0f) {
            float e = __expf(aRel);
            float s = 0.0f;
            #pragma unroll
            for (int i = 0; i < K_; ++i)
                s = fmaf(__shfl(e, i, 64), ET[i], s);
            float raw = __logf(s) + se[t * K_ + jc];
            float rr  = __shfl(raw, 0, 64);
            aRel = raw - rr;
            C   += rr;
        }
    }

    float contrib = (lane < K_) ? __expf(aRel + endT[jc]) : 0.0f;
    #pragma unroll
    for (int off = 32; off >= 1; off >>= 1) contrib += __shfl_xor(contrib, off, 64);
    const float logZ = C + __logf(contrib);

    float sc = 0.0f, ms = 0.0f;
    for (int t = lane; t < T_; t += 64) {
        const float mt = sm[t];
        ms += mt;
        if (t < T_ - 1) {
            const int ct = st[t], nt2 = st[t + 1];
            sc += trans[ct * K_ + nt2] * sm[t + 1] + se[t * K_ + ct] * mt;
        }
    }
    #pragma unroll
    for (int off = 32; off >= 1; off >>= 1) {
        sc += __shfl_xor(sc, off, 64);
        ms += __shfl_xor(ms, off, 64);
    }
    if (lane == 0) {
        const int lastIdx = (int)ms - 1;
        const int lastTag = st[lastIdx];
        sc += startT[st[0]] + endT[lastTag] + se[(T_ - 1) * K_ + lastTag] * sm[T_ - 1];
        ws[b]      = sc - logZ;
        ws[B_ + b] = ms;
    }
}

// ---------------- Kernel 3: loss = -sum(ll) / sum(mask) ------------------------
__global__ __launch_bounds__(64) void fin_kernel(
    const float* __restrict__ ll, const float* __restrict__ msum,
    float* __restrict__ outF)
{
    const int lane = threadIdx.x;
    float l = ll[lane];
    float m = msum[lane];
    #pragma unroll
    for (int off = 32; off >= 1; off >>= 1) {
        l += __shfl_xor(l, off, 64);
        m += __shfl_xor(m, off, 64);
    }
    if (lane == 0) outF[0] = -l / m;
}

extern "C" void kernel_launch(void* const* d_in, const int* in_sizes, int n_in,
                              void* d_out, int out_size, void* d_ws, size_t ws_size,
                              hipStream_t stream) {
    const float* A     = (const float*)d_in[0];   // vectors [64,512,768] f32
    const int*   tags  = (const int*)  d_in[1];   // targets [64,512] i32
    const int*   mask  = (const int*)  d_in[2];   // mask    [64,512] i32
    const float* W     = (const float*)d_in[3];   // W [21,768] f32
    const float* bias  = (const float*)d_in[4];   // b [21]
    const float* trans = (const float*)d_in[5];   // transitions [21,21]
    const float* stT   = (const float*)d_in[6];   // start_trans [21]
    const float* enT   = (const float*)d_in[7];   // end_trans [21]
    float* outF = (float*)d_out;
    float* ws   = (float*)d_ws;

    proj_kernel<<<1024, 512, 0, stream>>>(A, W, bias, outF);

    // ws layout (floats): G[64*32*448] | SC[64*32] | ll[64] | ms[64]
    const size_t gFloats  = (size_t)B_ * NCHUNK * GSTRIDE;
    const size_t scOff    = gFloats;
    const size_t llOff    = gFloats + (size_t)B_ * NCHUNK;
    const size_t msOff    = llOff + B_;
    const size_t needBytes = (msOff + B_) * sizeof(float);

    if (ws_size >= needBytes) {
        float* G   = ws;
        float* SC  = ws + scOff;
        float* llp = ws + llOff;
        float* msv = ws + msOff;
        chunk_kernel<<<dim3(NCHUNK, B_), 64, 0, stream>>>(outF, mask, trans, G, SC);
        scan_kernel<<<B_, 64, 0, stream>>>(outF, tags, mask, trans, stT, enT, G, SC, llp, msv);
        fin_kernel<<<1, 64, 0, stream>>>(llp, msv, outF);
    } else {
        crf_kernel<<<B_, 64, 0, stream>>>(outF, tags, mask, trans, stT, enT, ws);
        fin_kernel<<<1, 64, 0, stream>>>(ws, ws + B_, outF);
    }
}